// Round 12
// baseline (313.712 us; speedup 1.0000x reference)
//
#include <hip/hip_runtime.h>
#include <stdint.h>

#define DIN   4096
#define DOUT  4096
#define MTOT  8192
#define NT    64                      /* K-tiles of BK=64 */

#define GRID_M 64                     /* M/128 */
#define GRID_N 16                     /* N/256 */
#define NWG    (GRID_M * GRID_N)      /* 1024; %8==0 -> bijective XCD swizzle */

typedef __attribute__((ext_vector_type(4)))  float        f32x4;
typedef __attribute__((ext_vector_type(16))) float        f32x16;
typedef __attribute__((ext_vector_type(4)))  int          i32x4;
typedef __attribute__((ext_vector_type(4)))  unsigned int u32x4;
typedef __attribute__((ext_vector_type(2)))  unsigned int u32x2;
typedef __attribute__((ext_vector_type(8)))  short        bf16x8;

__device__ __forceinline__ unsigned int pack_bf2_rne(float a, float b) {
  unsigned int ua = __builtin_bit_cast(unsigned int, a);
  unsigned int ub = __builtin_bit_cast(unsigned int, b);
  ua += 0x7fffu + ((ua >> 16) & 1u);
  ub += 0x7fffu + ((ub >> 16) & 1u);
  return (ua >> 16) | (ub & 0xffff0000u);
}

// (w - off) integer, |v| <= 135 < 256 -> exact in bf16.
__device__ __forceinline__ unsigned int pack_bf2_exact(int a, int b) {
  unsigned int ua = __builtin_bit_cast(unsigned int, (float)a);
  unsigned int ub = __builtin_bit_cast(unsigned int, (float)b);
  return (ua >> 16) | (ub & 0xffff0000u);
}

// ---- merged pre-pass (r10, proven): x->bf16 and (w-off)->bf16 into CHUNK-MAJOR
// 16KiB units: byte = ch*2048 + row*16 (ch = 16B k-chunk 0..7, row 0..127).
#define UNITS_A (GRID_M * NT)
#define UNITS_B (GRID_N * 2 * NT)
__global__ __launch_bounds__(256) void conv_kernel(const float* __restrict__ X,
                                                   u32x4* __restrict__ wsA,
                                                   const int* __restrict__ W,
                                                   const int* __restrict__ Off,
                                                   u32x4* __restrict__ wsB) {
  const int totA = UNITS_A * 1024;
  const int totB = UNITS_B * 1024;
  for (int idx = blockIdx.x * 256 + threadIdx.x; idx < totA + totB;
       idx += gridDim.x * 256) {
    if (idx < totA) {
      const int pos = idx & 1023;
      const int row = pos >> 3, ch = pos & 7;
      const int unit = idx >> 10;
      const int kt = unit & (NT - 1), rb = unit >> 6;
      const int m = rb * 128 + row;
      const f32x4* src = (const f32x4*)(X + ((long)m << 12) + kt * 64 + ch * 8);
      f32x4 f0 = src[0], f1 = src[1];
      u32x4 d;
      d[0] = pack_bf2_rne(f0[0], f0[1]);
      d[1] = pack_bf2_rne(f0[2], f0[3]);
      d[2] = pack_bf2_rne(f1[0], f1[1]);
      d[3] = pack_bf2_rne(f1[2], f1[3]);
      wsA[(long)unit * 1024 + ch * 128 + row] = d;
    } else {
      const int j = idx - totA;
      const int pos = j & 1023;
      const int row = pos >> 3, ch = pos & 7;
      const int unit = j >> 10;
      const int kt = unit & (NT - 1), nb = unit >> 6;
      const int n = nb * 128 + row;
      const i32x4* src = (const i32x4*)(W + ((long)n << 12) + kt * 64 + ch * 8);
      const int off = Off[n];
      i32x4 w0 = src[0], w1 = src[1];
      u32x4 d;
      d[0] = pack_bf2_exact(w0[0] - off, w0[1] - off);
      d[1] = pack_bf2_exact(w0[2] - off, w0[3] - off);
      d[2] = pack_bf2_exact(w1[0] - off, w1[1] - off);
      d[3] = pack_bf2_exact(w1[2] - off, w1[3] - off);
      wsB[(long)unit * 1024 + ch * 128 + row] = d;
    }
  }
}

// ======= 128x256-tile, 256-thr, 2-independent-blocks/CU GEMM (B-direct) =======
// 4 waves = 2M x 2N; wave output 64x128 = 2mt x 4nt of 32x32; acc f32x16[2][4].
// A via LDS (one 128-row chunk-major unit, double-buffered, 32 KiB total);
// B per-lane direct from wsB into bR[4][4] (full tile ahead).
// kk-major phases (4/tile): ph_kk = { 2 A ds_reads ; [stage/gate] ; cascade
//   LGKM(1)->4 MFMA(mt0), LGKM(0)->4 MFMA(mt1) ; BLOAD bR[kk]<-B(t+1) ; BAR }.
// vmcnt ledger (STAGE=2 loads, BLOAD=4; issue order ph0:stA0,Bk0' ph1:stA1,Bk1'
// ph2:Bk2' ph3:Bk3'; entering invariant 12 = Bk1,Bk2,Bk3(t)):
//   ph0: no gate (Bk0(t) retired by prev tile's end gate).
//   ph1: outstanding 20 -> WAITV(16) retires Bk1(t).
//   ph2: 20 -> WAITV(16) retires Bk2(t).   ph3: 20 -> WAITV(16) retires Bk3(t).
//   end: 18 -> WAITV(12) retires stA0,Bk0',stA1 => A(t+1) staging retired
//   BEFORE tile-end BAR (retire->BAR->read holds); leaves 12. QED.
// Tail tile 63: gates 8/4/0. Prologue: stA(4)+Bk0..3(16)=20 -> WAITV(12).
// A-buf WAR: reads of tile t-1 done at each wave's LGKM(0) before end BAR ->
// staging into that buffer next tile is safe (r10 argument).
// The CU's second, independent block (no shared barriers) fills gate stalls.

#define BAR()   __builtin_amdgcn_s_barrier()
#define SB()    __builtin_amdgcn_sched_barrier(0)
#define LGKM_(N) asm volatile("s_waitcnt lgkmcnt(" #N ")" ::: "memory")
#define LGKM(N)  LGKM_(N)
#define WAITV(N) asm volatile("s_waitcnt vmcnt(" #N ")" ::: "memory")

typedef __attribute__((address_space(3))) const char* ldsp;

#define DSR(dst, p, IMM) \
  asm volatile("ds_read_b128 %0, %1 offset:" #IMM : "=v"(dst) : "v"(p))

// stage half h (8 KiB) of A(t+1)'s unit: 2 global_load_lds x 256 thr
#define STAGE(bufc, h, t)                                                       \
  { const u32x4* s_ = bA + (long)(t) * 1024 + (h) * 512;                        \
    _Pragma("unroll")                                                           \
    for (int i_ = 0; i_ < 2; ++i_) {                                            \
      const int o_ = tid + i_ * 256;                                            \
      __builtin_amdgcn_global_load_lds(                                         \
          (const __attribute__((address_space(1))) void*)(s_ + o_),             \
          (__attribute__((address_space(3))) void*)(&ldsA[bufc][(h) * 512] + o_),\
          16, 0, 0);                                                            \
    } }

// B(t+1)[kk]: four coalesced 16B per-lane loads (nt=0..3)
#define BLOAD(kk, t)                                                            \
  { const char* pk_ = bBw + (long)((t) + 1) * 16384 + (kk) * 4096;              \
    asm volatile("global_load_dwordx4 %0, %1, off"                              \
                 : "=v"(bR[kk][0]) : "v"(pk_));                                 \
    asm volatile("global_load_dwordx4 %0, %1, off offset:512"                   \
                 : "=v"(bR[kk][1]) : "v"(pk_));                                 \
    asm volatile("global_load_dwordx4 %0, %1, off offset:1024"                  \
                 : "=v"(bR[kk][2]) : "v"(pk_));                                 \
    asm volatile("global_load_dwordx4 %0, %1, off offset:1536"                  \
                 : "=v"(bR[kk][3]) : "v"(pk_)); }

#define MMA4(mt, kk)                                                            \
  { _Pragma("unroll") for (int n_ = 0; n_ < 4; ++n_)                            \
      acc[mt][n_] = __builtin_amdgcn_mfma_f32_32x32x16_bf16(                    \
          aR[mt], bR[kk][n_], acc[mt][n_], 0, 0, 0); }

#define CASC(kk)                                                                \
  __builtin_amdgcn_s_setprio(1);                                                \
  LGKM(1); SB(); MMA4(0, kk)                                                    \
  LGKM(0); SB(); MMA4(1, kk)                                                    \
  __builtin_amdgcn_s_setprio(0);

#define TILE(pA_, ABUF, t, SG, W1, W2, W3, WE)                                  \
  DSR(aR[0], pA_, 0); DSR(aR[1], pA_, 512);                                     \
  if (SG) { STAGE(ABUF, 0, (t) + 1) }                                           \
  CASC(0)                                                                       \
  if (SG) { BLOAD(0, t) }                                                       \
  BAR();                                                                        \
  DSR(aR[0], pA_, 4096); DSR(aR[1], pA_, 4608);                                 \
  if (SG) { STAGE(ABUF, 1, (t) + 1) }                                           \
  W1; CASC(1)                                                                   \
  if (SG) { BLOAD(1, t) }                                                       \
  BAR();                                                                        \
  DSR(aR[0], pA_, 8192); DSR(aR[1], pA_, 8704);                                 \
  W2; CASC(2)                                                                   \
  if (SG) { BLOAD(2, t) }                                                       \
  BAR();                                                                        \
  DSR(aR[0], pA_, 12288); DSR(aR[1], pA_, 12800);                               \
  W3; CASC(3)                                                                   \
  if (SG) { BLOAD(3, t) }                                                       \
  WE; BAR();

__global__ __launch_bounds__(256, 2) void gemm4_kernel(
    const u32x4* __restrict__ wsA, const u32x4* __restrict__ wsB,
    const float* __restrict__ Scale, float* __restrict__ Out) {
  __shared__ u32x4 ldsA[2][1024];   // A only: [buf][ch*128+row] = 32 KiB

  const int tid  = threadIdx.x;
  const int lane = tid & 63;
  const int wid  = tid >> 6;       // 0..3
  const int wrM  = wid >> 1;       // 0..1 : 64-row half of the 128-row tile
  const int wcN  = wid & 1;        // 0..1 : 128-col half (one B unit)
  const int lane31 = lane & 31;
  const int lhi    = lane >> 5;

  int gid = (int)blockIdx.x;
  gid = (gid & 7) * (NWG >> 3) + (gid >> 3);   // bijective XCD swizzle
  const int wg_m = gid / GRID_N;               // 0..63
  const int wg_n = gid % GRID_N;               // 0..15

  const int lanepA = (wrM * 64 + lane31) * 16 + lhi * 2048;
  ldsp pA0 = (ldsp)((const char*)&ldsA[0][0] + lanepA);
  ldsp pA1 = (ldsp)((const char*)&ldsA[1][0] + lanepA);

  const u32x4* bA = wsA + (long)wg_m * NT * 1024;
  const char* bBw = (const char*)(wsB + (long)(wg_n * 2 + wcN) * NT * 1024)
                  + lane31 * 16 + lhi * 2048;

  f32x16 acc[2][4];
#pragma unroll
  for (int m = 0; m < 2; ++m)
#pragma unroll
    for (int n = 0; n < 4; ++n)
#pragma unroll
      for (int q = 0; q < 16; ++q) acc[m][n][q] = 0.f;

  bf16x8 aR[2], bR[4][4];

  // prologue: stage A(0) (4 loads) + B(0) (16); WAITV(12) retires stA+Bk0 ->
  // leaves Bk1,Bk2,Bk3 = 12 = steady entering invariant.
  STAGE(0, 0, 0) STAGE(0, 1, 0)
  BLOAD(0, -1) BLOAD(1, -1) BLOAD(2, -1) BLOAD(3, -1)
  WAITV(12); BAR();

#pragma unroll 1
  for (int it = 0; it < 31; ++it) {            // tiles 0..61
    const int t = 2 * it;
    TILE(pA0, 1, t,     1, WAITV(16), WAITV(16), WAITV(16), WAITV(12))
    TILE(pA1, 0, t + 1, 1, WAITV(16), WAITV(16), WAITV(16), WAITV(12))
  }
  TILE(pA0, 1, 62, 1, WAITV(16), WAITV(16), WAITV(16), WAITV(12))
  TILE(pA1, 0, 63, 0, WAITV(8),  WAITV(4),  WAITV(0),  )

  // epilogue: out = acc * scale[col]
  // 32x32 C/D map (m74/m101): col = lane&31, row = (reg&3)+8*(reg>>2)+4*(lane>>5)
  const int col0 = wg_n * 256 + wcN * 128 + lane31;
  const int row0 = wg_m * 128 + wrM * 64 + lhi * 4;
#pragma unroll
  for (int nt = 0; nt < 4; ++nt) {
    const int col = col0 + nt * 32;
    const float s = Scale[col];
#pragma unroll
    for (int mt = 0; mt < 2; ++mt) {
      const int rb = row0 + mt * 32;
#pragma unroll
      for (int q = 0; q < 4; ++q)
#pragma unroll
        for (int j = 0; j < 4; ++j)
          Out[(long)(rb + q * 8 + j) * DOUT + col] = acc[mt][nt][q * 4 + j] * s;
    }
  }
}

// ================= fallback: fused 128x128 (round-1, proven) =================
__global__ __launch_bounds__(256, 2) void gemm_fused_kernel(
    const float* __restrict__ X, const int* __restrict__ W,
    const int* __restrict__ Off, const float* __restrict__ Scale,
    float* __restrict__ Out) {
  __shared__ char ldsA[2][128 * 64 * 2];
  __shared__ char ldsB[2][128 * 64 * 2];

  const int tid  = threadIdx.x;
  const int lane = tid & 63;
  const int wid  = tid >> 6;
  const int fwr  = wid >> 1;
  const int fwc  = wid & 1;

  int gid = (int)blockIdx.x;
  gid = (gid & 7) * (2048 >> 3) + (gid >> 3);
  const int wg_m = gid / 32;
  const int wg_n = gid % 32;
  const int brow = wg_m * 128;
  const int bcol = wg_n * 128;

  f32x4 acc[4][4];
#pragma unroll
  for (int m = 0; m < 4; ++m)
#pragma unroll
    for (int n = 0; n < 4; ++n) acc[m][n] = (f32x4){0.f, 0.f, 0.f, 0.f};

  int aoff[2][4], boff[2][4];
#pragma unroll
  for (int kk = 0; kk < 2; ++kk)
#pragma unroll
    for (int m = 0; m < 4; ++m) {
      const int kb = kk * 64 + ((lane >> 4) << 4);
      const int ra = fwr * 64 + m * 16 + (lane & 15);
      const int rb = fwc * 64 + m * 16 + (lane & 15);
      aoff[kk][m] = ra * 128 + (kb ^ ((ra & 7) << 4));
      boff[kk][m] = rb * 128 + (kb ^ ((rb & 7) << 4));
    }

  long xo[8], wo[8];
  int lo[8], ofv[8];
#pragma unroll
  for (int i = 0; i < 8; ++i) {
    const int idx = tid + i * 256;
    const int row = idx >> 4, c4 = idx & 15;
    xo[i] = (long)(brow + row) * DIN + c4 * 4;
    wo[i] = (long)(bcol + row) * DIN + c4 * 4;
    lo[i] = row * 128 + ((c4 * 8) ^ ((row & 7) << 4));
    ofv[i] = Off[bcol + row];
  }
  {
#pragma unroll
    for (int i = 0; i < 8; ++i) {
      f32x4 f = *(const f32x4*)(X + xo[i]);
      u32x2 d;
      d[0] = pack_bf2_rne(f[0], f[1]);
      d[1] = pack_bf2_rne(f[2], f[3]);
      *(u32x2*)(&ldsA[0][lo[i]]) = d;
    }
#pragma unroll
    for (int i = 0; i < 8; ++i) {
      i32x4 w = *(const i32x4*)(W + wo[i]);
      u32x2 d;
      d[0] = pack_bf2_exact(w[0] - ofv[i], w[1] - ofv[i]);
      d[1] = pack_bf2_exact(w[2] - ofv[i], w[3] - ofv[i]);
      *(u32x2*)(&ldsB[0][lo[i]]) = d;
    }
  }
  __syncthreads();
#pragma unroll 1
  for (int kt = 0; kt < NT; ++kt) {
    const int cur = kt & 1;
    const bool pf = (kt + 1 < NT);
    f32x4 fa[8];
    i32x4 fb[8];
    if (pf) {
      const int ko = (kt + 1) * 64;
#pragma unroll
      for (int i = 0; i < 8; ++i) fa[i] = *(const f32x4*)(X + xo[i] + ko);
#pragma unroll
      for (int i = 0; i < 8; ++i) fb[i] = *(const i32x4*)(W + wo[i] + ko);
    }
#pragma unroll
    for (int kk = 0; kk < 2; ++kk) {
      bf16x8 fa2[4], fb2[4];
#pragma unroll
      for (int m = 0; m < 4; ++m)
        fa2[m] = __builtin_bit_cast(bf16x8, *(const u32x4*)(&ldsA[cur][aoff[kk][m]]));
#pragma unroll
      for (int n = 0; n < 4; ++n)
        fb2[n] = __builtin_bit_cast(bf16x8, *(const u32x4*)(&ldsB[cur][boff[kk][n]]));
#pragma unroll
      for (int m = 0; m < 4; ++m)
#pragma unroll
        for (int n = 0; n < 4; ++n)
          acc[m][n] = __builtin_amdgcn_mfma_f32_16x16x32_bf16(fa2[m], fb2[n], acc[m][n], 0, 0, 0);
    }
    if (pf) {
      char* dA = ldsA[cur ^ 1];
      char* dB = ldsB[cur ^ 1];
#pragma unroll
      for (int i = 0; i < 8; ++i) {
        u32x2 d;
        d[0] = pack_bf2_rne(fa[i][0], fa[i][1]);
        d[1] = pack_bf2_rne(fa[i][2], fa[i][3]);
        *(u32x2*)(&dA[lo[i]]) = d;
      }
#pragma unroll
      for (int i = 0; i < 8; ++i) {
        u32x2 d;
        d[0] = pack_bf2_exact(fb[i][0] - ofv[i], fb[i][1] - ofv[i]);
        d[1] = pack_bf2_exact(fb[i][2] - ofv[i], fb[i][3] - ofv[i]);
        *(u32x2*)(&dB[lo[i]]) = d;
      }
    }
    __syncthreads();
  }

  const int col0 = bcol + fwc * 64 + (lane & 15);
  const int row0 = brow + fwr * 64 + ((lane >> 4) << 2);
#pragma unroll
  for (int n = 0; n < 4; ++n) {
    const int col = col0 + n * 16;
    const float s = Scale[col];
#pragma unroll
    for (int m = 0; m < 4; ++m) {
      const int r = row0 + m * 16;
#pragma unroll
      for (int j = 0; j < 4; ++j)
        Out[(long)(r + j) * DOUT + col] = acc[m][n][j] * s;
    }
  }
}

extern "C" void kernel_launch(void* const* d_in, const int* in_sizes, int n_in,
                              void* d_out, int out_size, void* d_ws, size_t ws_size,
                              hipStream_t stream) {
  (void)in_sizes; (void)n_in; (void)out_size;
  const float* X  = (const float*)d_in[0];
  const int*   W  = (const int*)d_in[1];
  const float* Sc = (const float*)d_in[2];
  const int*   Of = (const int*)d_in[3];
  float* Out = (float*)d_out;

  const size_t needA = (size_t)MTOT * DIN * 2;
  const size_t needB = (size_t)DOUT * DIN * 2;
  if (ws_size >= needA + needB) {
    u32x4* wsA = (u32x4*)d_ws;
    u32x4* wsB = (u32x4*)((char*)d_ws + needA);
    conv_kernel<<<3072, 256, 0, stream>>>(X, wsA, W, Of, wsB);
    gemm4_kernel<<<NWG, 256, 0, stream>>>(wsA, wsB, Sc, Out);
  } else {
    gemm_fused_kernel<<<2048, 256, 0, stream>>>(X, W, Of, Sc, Out);
  }
}

// Round 13
// 270.105 us; speedup vs baseline: 1.1614x; 1.1614x over previous
//
#include <hip/hip_runtime.h>
#include <stdint.h>

#define DIN   4096
#define DOUT  4096
#define MTOT  8192
#define NT    64                      /* K-tiles of BK=64 */

#define BM    256
#define BN    256
#define GRID_M (MTOT / BM)            /* 32 */
#define GRID_N (DOUT / BN)            /* 16 */
#define NWG   (GRID_M * GRID_N)       /* 512 */

typedef __attribute__((ext_vector_type(4))) float        f32x4;
typedef __attribute__((ext_vector_type(4))) int          i32x4;
typedef __attribute__((ext_vector_type(4))) unsigned int u32x4;
typedef __attribute__((ext_vector_type(2))) unsigned int u32x2;
typedef __attribute__((ext_vector_type(8))) short        bf16x8;

__device__ __forceinline__ unsigned int pack_bf2_rne(float a, float b) {
  unsigned int ua = __builtin_bit_cast(unsigned int, a);
  unsigned int ub = __builtin_bit_cast(unsigned int, b);
  ua += 0x7fffu + ((ua >> 16) & 1u);
  ub += 0x7fffu + ((ub >> 16) & 1u);
  return (ua >> 16) | (ub & 0xffff0000u);
}

// (w - off) integer, |v| <= 135 < 256 -> exact in bf16.
__device__ __forceinline__ unsigned int pack_bf2_exact(int a, int b) {
  unsigned int ua = __builtin_bit_cast(unsigned int, (float)a);
  unsigned int ub = __builtin_bit_cast(unsigned int, (float)b);
  return (ua >> 16) | (ub & 0xffff0000u);
}

// ---- merged pre-pass (r8, proven): x->bf16 and (w-off)->bf16, 16KiB units of
// [128 rows][64 k], pre-swizzled: byte layout row*128 + ((chunk*16)^((row&7)<<4))
#define TOTA (MTOT * (DIN / 8))
#define TOTB (DOUT * (DIN / 8))
__global__ __launch_bounds__(256) void conv_kernel(const float* __restrict__ X,
                                                   u32x4* __restrict__ wsA,
                                                   const int* __restrict__ W,
                                                   const int* __restrict__ Off,
                                                   u32x4* __restrict__ wsB) {
  for (int idx = blockIdx.x * 256 + threadIdx.x; idx < TOTA + TOTB;
       idx += gridDim.x * 256) {
    if (idx < TOTA) {
      const int m  = idx >> 9;
      const int c  = idx & 511;
      const int kt = c >> 3, ch = c & 7;
      const int rb = m >> 7, row = m & 127;
      const f32x4* src = (const f32x4*)(X + ((long)m << 12) + kt * 64 + ch * 8);
      f32x4 f0 = src[0], f1 = src[1];
      u32x4 d;
      d[0] = pack_bf2_rne(f0[0], f0[1]);
      d[1] = pack_bf2_rne(f0[2], f0[3]);
      d[2] = pack_bf2_rne(f1[0], f1[1]);
      d[3] = pack_bf2_rne(f1[2], f1[3]);
      wsA[(long)(rb * NT + kt) * 1024 + row * 8 + (ch ^ (row & 7))] = d;
    } else {
      const int j  = idx - TOTA;
      const int n  = j >> 9;
      const int c  = j & 511;
      const int kt = c >> 3, ch = c & 7;
      const int nb = n >> 7, row = n & 127;
      const i32x4* src = (const i32x4*)(W + ((long)n << 12) + kt * 64 + ch * 8);
      const int off = Off[n];
      i32x4 w0 = src[0], w1 = src[1];
      u32x4 d;
      d[0] = pack_bf2_exact(w0[0] - off, w0[1] - off);
      d[1] = pack_bf2_exact(w0[2] - off, w0[3] - off);
      d[2] = pack_bf2_exact(w1[0] - off, w1[1] - off);
      d[3] = pack_bf2_exact(w1[2] - off, w1[3] - off);
      wsB[(long)(nb * NT + kt) * 1024 + row * 8 + (ch ^ (row & 7))] = d;
    }
  }
}

// ====== r8 GEMM + m201 C-QUADRANT phase decomposition (12/4/8/0 reads) ======
// Phase = C-quadrant (64 rows x 32 cols) x full K=64:
//  ph1: rd B-lo(4)+A-lo(8) ; stage A0(t+1)->ABUF ; LGKM0 ; 16 MFMA aPxbP ; BAR
//  ph2: rd B-hi(4)         ; stage A1(t+1)->ABUF ; LGKM0 ; 16 MFMA aPxbQ ; BAR
//  ph3: rd A-hi(8)         ; stage B0(t+2)->BBUF ; LGKM0 ; 16 MFMA aQxbP ; BAR
//  ph4: (no reads)         ; stage B1(t+2)->BBUF ; WAITV(4) ; 16 MFMA aQxbQ ; BAR
// A-frags persist 2 phases, B-frags 2; ph4 is read-free (pure MFMA under the
// vmcnt gate). Ledgers identical to r8 (proven): B of current buf fully read by
// ph2's LGKM0 + BAR -> ph3/4 staging into it WAR-safe; A(t+1) -> other buffer;
// WAITV(4) at ph4 (12 outstanding, retires 8 = all of t+1) precedes the end-BAR
// -> retire->BAR->read holds. Tail: WAITV(0) at t=62, t=63 compute-only.

#define BAR()   __builtin_amdgcn_s_barrier()
#define SB()    __builtin_amdgcn_sched_barrier(0)
#define LGKM0() asm volatile("s_waitcnt lgkmcnt(0)" ::: "memory")
#define WAITV(N) asm volatile("s_waitcnt vmcnt(" #N ")" ::: "memory")

typedef __attribute__((address_space(3))) const char* ldsp;

#define DSR(dst, p, IMM) \
  asm volatile("ds_read_b128 %0, %1 offset:" #IMM : "=v"(dst) : "v"(p))

#define STAGE(ldsArr, bufc, h, basePtr, t)                                      \
  { const u32x4* s_ = (basePtr) + (long)(t) * 1024;                             \
    _Pragma("unroll")                                                           \
    for (int i_ = 0; i_ < 2; ++i_) {                                            \
      const int o_ = tid + i_ * 512;                                            \
      __builtin_amdgcn_global_load_lds(                                         \
          (const __attribute__((address_space(1))) void*)(s_ + o_),             \
          (__attribute__((address_space(3))) void*)(&ldsArr[bufc][h][0][0] + o_),\
          16, 0, 0);                                                            \
    } }

// A rows 0..63 (4 m-frags) x both k-halves
#define RD_A_LO(pAc0, pAc1)                                                     \
  DSR(aP[0][0], pAc0, 0);    DSR(aP[1][0], pAc0, 2048);                         \
  DSR(aP[2][0], pAc0, 4096); DSR(aP[3][0], pAc0, 6144);                         \
  DSR(aP[0][1], pAc1, 0);    DSR(aP[1][1], pAc1, 2048);                         \
  DSR(aP[2][1], pAc1, 4096); DSR(aP[3][1], pAc1, 6144);
// A rows 64..127
#define RD_A_HI(pAc0, pAc1)                                                     \
  DSR(aQ[0][0], pAc0, 8192);  DSR(aQ[1][0], pAc0, 10240);                       \
  DSR(aQ[2][0], pAc0, 12288); DSR(aQ[3][0], pAc0, 14336);                       \
  DSR(aQ[0][1], pAc1, 8192);  DSR(aQ[1][1], pAc1, 10240);                       \
  DSR(aQ[2][1], pAc1, 12288); DSR(aQ[3][1], pAc1, 14336);
// B cols 0..31 (2 n-frags) x both k-halves
#define RD_B_LO(pBc0, pBc1)                                                     \
  DSR(bP[0][0], pBc0, 0); DSR(bP[1][0], pBc0, 2048);                            \
  DSR(bP[0][1], pBc1, 0); DSR(bP[1][1], pBc1, 2048);
// B cols 32..63
#define RD_B_HI(pBc0, pBc1)                                                     \
  DSR(bQ[0][0], pBc0, 4096); DSR(bQ[1][0], pBc0, 6144);                         \
  DSR(bQ[0][1], pBc1, 4096); DSR(bQ[1][1], pBc1, 6144);

#define MMA16Q(aS_, bS_, mb, nb)                                                \
  __builtin_amdgcn_s_setprio(1);                                                \
  { _Pragma("unroll") for (int k_ = 0; k_ < 2; ++k_)                            \
    { _Pragma("unroll") for (int m_ = 0; m_ < 4; ++m_)                          \
      { _Pragma("unroll") for (int n_ = 0; n_ < 2; ++n_)                        \
          acc[(mb) + m_][(nb) + n_] = __builtin_amdgcn_mfma_f32_16x16x32_bf16(  \
              aS_[m_][k_], bS_[n_][k_], acc[(mb) + m_][(nb) + n_], 0, 0, 0);    \
  } } }                                                                         \
  __builtin_amdgcn_s_setprio(0);

#define TILE(pAc0, pAc1, pBc0, pBc1, ABUF, BBUF, t, SA, SBf, WV)                \
  RD_B_LO(pBc0, pBc1) RD_A_LO(pAc0, pAc1)                                       \
  if (SA) { STAGE(ldsA, ABUF, 0, bA0, (t) + 1) }                                \
  LGKM0(); SB(); MMA16Q(aP, bP, 0, 0) BAR();                                    \
  RD_B_HI(pBc0, pBc1)                                                           \
  if (SA) { STAGE(ldsA, ABUF, 1, bA1, (t) + 1) }                                \
  LGKM0(); SB(); MMA16Q(aP, bQ, 0, 2) BAR();                                    \
  RD_A_HI(pAc0, pAc1)                                                           \
  if (SBf) { STAGE(ldsB, BBUF, 0, bB0, (t) + 2) }                               \
  LGKM0(); SB(); MMA16Q(aQ, bP, 4, 0) BAR();                                    \
  if (SBf) { STAGE(ldsB, BBUF, 1, bB1, (t) + 2) }                               \
  WV; SB(); MMA16Q(aQ, bQ, 4, 2) BAR();

__global__ __launch_bounds__(512, 2) void gemm8_kernel(
    const u32x4* __restrict__ wsA, const u32x4* __restrict__ wsB,
    const float* __restrict__ Scale, float* __restrict__ Out) {
  __shared__ u32x4 ldsA[2][2][128][8];   // [buf][half][row][chunk16] = 64 KiB
  __shared__ u32x4 ldsB[2][2][128][8];

  const int tid  = threadIdx.x;
  const int lane = tid & 63;
  const int wid  = tid >> 6;
  const int wr   = wid >> 2;     // A half
  const int wc   = wid & 3;      // 64-col N slice
  const int wch  = wc >> 1;      // B half
  const int wcl  = wc & 1;

  int gid = (int)blockIdx.x;
  gid = (gid & 7) * (NWG >> 3) + (gid >> 3);   // bijective XCD swizzle (512%8==0)
  const int wg_m = gid / GRID_N;
  const int wg_n = gid % GRID_N;

  const int riA = lane & 15;
  const int c0  = lane >> 4;
  const int cs0 = c0 ^ (riA & 7);              // logical chunk c0   ^ row-swz
  const int cs1 = (4 + c0) ^ (riA & 7);        // logical chunk 4+c0 ^ row-swz

  // per-wave LDS read base pointers (AS3, 32-bit); m strides are literal offsets
  ldsp pA0c0 = (ldsp)&ldsA[0][wr][riA][cs0];
  ldsp pA0c1 = (ldsp)&ldsA[0][wr][riA][cs1];
  ldsp pA1c0 = (ldsp)&ldsA[1][wr][riA][cs0];
  ldsp pA1c1 = (ldsp)&ldsA[1][wr][riA][cs1];
  ldsp pB0c0 = (ldsp)&ldsB[0][wch][wcl * 64 + riA][cs0];
  ldsp pB0c1 = (ldsp)&ldsB[0][wch][wcl * 64 + riA][cs1];
  ldsp pB1c0 = (ldsp)&ldsB[1][wch][wcl * 64 + riA][cs0];
  ldsp pB1c1 = (ldsp)&ldsB[1][wch][wcl * 64 + riA][cs1];

  const u32x4* bA0 = wsA + (long)(wg_m * 2 + 0) * NT * 1024;
  const u32x4* bA1 = wsA + (long)(wg_m * 2 + 1) * NT * 1024;
  const u32x4* bB0 = wsB + (long)(wg_n * 2 + 0) * NT * 1024;
  const u32x4* bB1 = wsB + (long)(wg_n * 2 + 1) * NT * 1024;

  f32x4 acc[8][4];
#pragma unroll
  for (int m = 0; m < 8; ++m)
#pragma unroll
    for (int n = 0; n < 4; ++n) acc[m][n] = (f32x4){0.f, 0.f, 0.f, 0.f};

  bf16x8 aP[4][2], aQ[4][2], bP[2][2], bQ[2][2];

  // prologue: tile0 all 4 half-tiles + tile1 B halves; retire tile0 (vmcnt(4))
  STAGE(ldsB, 0, 0, bB0, 0) STAGE(ldsA, 0, 0, bA0, 0)
  STAGE(ldsB, 0, 1, bB1, 0) STAGE(ldsA, 0, 1, bA1, 0)
  STAGE(ldsB, 1, 0, bB0, 1) STAGE(ldsB, 1, 1, bB1, 1)
  WAITV(4); BAR();

#pragma unroll 1
  for (int it = 0; it < 31; ++it) {            // tiles 0..61
    const int t = 2 * it;
    TILE(pA0c0, pA0c1, pB0c0, pB0c1, 1, 0, t,     1, 1, WAITV(4))
    TILE(pA1c0, pA1c1, pB1c0, pB1c1, 0, 1, t + 1, 1, 1, WAITV(4))
  }
  TILE(pA0c0, pA0c1, pB0c0, pB0c1, 1, 0, 62, 1, 0, WAITV(0))  // stage A(63), drain
  TILE(pA1c0, pA1c1, pB1c0, pB1c1, 0, 1, 63, 0, 0, )          // compute only

  // epilogue: out = acc * scale[col]; C/D map: col=lane&15, row=(lane>>4)*4+j
  const int col0 = wg_n * BN + wc * 64 + (lane & 15);
  const int row0 = wg_m * BM + wr * 128 + ((lane >> 4) << 2);
#pragma unroll
  for (int n = 0; n < 4; ++n) {
    const int col = col0 + n * 16;
    const float s = Scale[col];
#pragma unroll
    for (int m = 0; m < 8; ++m) {
      const int r = row0 + m * 16;
#pragma unroll
      for (int j = 0; j < 4; ++j)
        Out[(long)(r + j) * DOUT + col] = acc[m][n][j] * s;
    }
  }
}

// ================= fallback: fused 128x128 (round-1, proven) =================
__global__ __launch_bounds__(256, 2) void gemm_fused_kernel(
    const float* __restrict__ X, const int* __restrict__ W,
    const int* __restrict__ Off, const float* __restrict__ Scale,
    float* __restrict__ Out) {
  __shared__ char ldsA[2][128 * 64 * 2];
  __shared__ char ldsB[2][128 * 64 * 2];

  const int tid  = threadIdx.x;
  const int lane = tid & 63;
  const int wid  = tid >> 6;
  const int fwr  = wid >> 1;
  const int fwc  = wid & 1;

  int gid = (int)blockIdx.x;
  gid = (gid & 7) * (2048 >> 3) + (gid >> 3);
  const int wg_m = gid / 32;
  const int wg_n = gid % 32;
  const int brow = wg_m * 128;
  const int bcol = wg_n * 128;

  f32x4 acc[4][4];
#pragma unroll
  for (int m = 0; m < 4; ++m)
#pragma unroll
    for (int n = 0; n < 4; ++n) acc[m][n] = (f32x4){0.f, 0.f, 0.f, 0.f};

  int aoff[2][4], boff[2][4];
#pragma unroll
  for (int kk = 0; kk < 2; ++kk)
#pragma unroll
    for (int m = 0; m < 4; ++m) {
      const int kb = kk * 64 + ((lane >> 4) << 4);
      const int ra = fwr * 64 + m * 16 + (lane & 15);
      const int rb = fwc * 64 + m * 16 + (lane & 15);
      aoff[kk][m] = ra * 128 + (kb ^ ((ra & 7) << 4));
      boff[kk][m] = rb * 128 + (kb ^ ((rb & 7) << 4));
    }

  long xo[8], wo[8];
  int lo[8], ofv[8];
#pragma unroll
  for (int i = 0; i < 8; ++i) {
    const int idx = tid + i * 256;
    const int row = idx >> 4, c4 = idx & 15;
    xo[i] = (long)(brow + row) * DIN + c4 * 4;
    wo[i] = (long)(bcol + row) * DIN + c4 * 4;
    lo[i] = row * 128 + ((c4 * 8) ^ ((row & 7) << 4));
    ofv[i] = Off[bcol + row];
  }
  {
#pragma unroll
    for (int i = 0; i < 8; ++i) {
      f32x4 f = *(const f32x4*)(X + xo[i]);
      u32x2 d;
      d[0] = pack_bf2_rne(f[0], f[1]);
      d[1] = pack_bf2_rne(f[2], f[3]);
      *(u32x2*)(&ldsA[0][lo[i]]) = d;
    }
#pragma unroll
    for (int i = 0; i < 8; ++i) {
      i32x4 w = *(const i32x4*)(W + wo[i]);
      u32x2 d;
      d[0] = pack_bf2_exact(w[0] - ofv[i], w[1] - ofv[i]);
      d[1] = pack_bf2_exact(w[2] - ofv[i], w[3] - ofv[i]);
      *(u32x2*)(&ldsB[0][lo[i]]) = d;
    }
  }
  __syncthreads();
#pragma unroll 1
  for (int kt = 0; kt < NT; ++kt) {
    const int cur = kt & 1;
    const bool pf = (kt + 1 < NT);
    f32x4 fa[8];
    i32x4 fb[8];
    if (pf) {
      const int ko = (kt + 1) * 64;
#pragma unroll
      for (int i = 0; i < 8; ++i) fa[i] = *(const f32x4*)(X + xo[i] + ko);
#pragma unroll
      for (int i = 0; i < 8; ++i) fb[i] = *(const i32x4*)(W + wo[i] + ko);
    }
#pragma unroll
    for (int kk = 0; kk < 2; ++kk) {
      bf16x8 fa2[4], fb2[4];
#pragma unroll
      for (int m = 0; m < 4; ++m)
        fa2[m] = __builtin_bit_cast(bf16x8, *(const u32x4*)(&ldsA[cur][aoff[kk][m]]));
#pragma unroll
      for (int n = 0; n < 4; ++n)
        fb2[n] = __builtin_bit_cast(bf16x8, *(const u32x4*)(&ldsB[cur][boff[kk][n]]));
#pragma unroll
      for (int m = 0; m < 4; ++m)
#pragma unroll
        for (int n = 0; n < 4; ++n)
          acc[m][n] = __builtin_amdgcn_mfma_f32_16x16x32_bf16(fa2[m], fb2[n], acc[m][n], 0, 0, 0);
    }
    if (pf) {
      char* dA = ldsA[cur ^ 1];
      char* dB = ldsB[cur ^ 1];
#pragma unroll
      for (int i = 0; i < 8; ++i) {
        u32x2 d;
        d[0] = pack_bf2_rne(fa[i][0], fa[i][1]);
        d[1] = pack_bf2_rne(fa[i][2], fa[i][3]);
        *(u32x2*)(&dA[lo[i]]) = d;
      }
#pragma unroll
      for (int i = 0; i < 8; ++i) {
        u32x2 d;
        d[0] = pack_bf2_exact(fb[i][0] - ofv[i], fb[i][1] - ofv[i]);
        d[1] = pack_bf2_exact(fb[i][2] - ofv[i], fb[i][3] - ofv[i]);
        *(u32x2*)(&dB[lo[i]]) = d;
      }
    }
    __syncthreads();
  }

  const int col0 = bcol + fwc * 64 + (lane & 15);
  const int row0 = brow + fwr * 64 + ((lane >> 4) << 2);
#pragma unroll
  for (int n = 0; n < 4; ++n) {
    const int col = col0 + n * 16;
    const float s = Scale[col];
#pragma unroll
    for (int m = 0; m < 4; ++m) {
      const int r = row0 + m * 16;
#pragma unroll
      for (int j = 0; j < 4; ++j)
        Out[(long)(r + j) * DOUT + col] = acc[m][n][j] * s;
    }
  }
}

extern "C" void kernel_launch(void* const* d_in, const int* in_sizes, int n_in,
                              void* d_out, int out_size, void* d_ws, size_t ws_size,
                              hipStream_t stream) {
  (void)in_sizes; (void)n_in; (void)out_size;
  const float* X  = (const float*)d_in[0];
  const int*   W  = (const int*)d_in[1];
  const float* Sc = (const float*)d_in[2];
  const int*   Of = (const int*)d_in[3];
  float* Out = (float*)d_out;

  const size_t needA = (size_t)MTOT * DIN * 2;
  const size_t needB = (size_t)DOUT * DIN * 2;
  if (ws_size >= needA + needB) {
    u32x4* wsA = (u32x4*)d_ws;
    u32x4* wsB = (u32x4*)((char*)d_ws + needA);
    conv_kernel<<<3072, 256, 0, stream>>>(X, wsA, W, Of, wsB);
    gemm8_kernel<<<NWG, 512, 0, stream>>>(wsA, wsB, Sc, Out);
  } else {
    gemm_fused_kernel<<<2048, 256, 0, stream>>>(X, W, Of, Sc, Out);
  }
}